// Round 5
// baseline (259.869 us; speedup 1.0000x reference)
//
#include <hip/hip_runtime.h>
#include <stdint.h>

#define NUM_KP 17
#define BATCH  32
#define HDIM   256
#define WDIM   256
#define NCH    (BATCH * NUM_KP)     // 544 channels
#define MAXP   30
#define CAP    8192                 // per-channel candidate cap (E≈7340, sigma≲80 -> +10 sigma)

// 12-bit score quantization: q = (float_bits >> 13) - QB, clamped [1, 4095].
// Scores in (0.1, 1] map to bins [613, 4095]; ~32 candidates in the top bin
// for uniform-noise NMS maxima -> survivors ~= 30 + 32 +- 6 << 256.
#define NBINS  4096
#define QB     125953               // (0x3F800000 >> 13) - 4095

__device__ __forceinline__ unsigned long long shfl_down_u64(unsigned long long v, int off) {
    unsigned lo = (unsigned)v, hi = (unsigned)(v >> 32);
    lo = __shfl_down(lo, off);
    hi = __shfl_down(hi, off);
    return ((unsigned long long)hi << 32) | lo;
}
__device__ __forceinline__ unsigned long long shfl_u64(unsigned long long v, int lane) {
    unsigned lo = (unsigned)v, hi = (unsigned)(v >> 32);
    lo = __shfl(lo, lane);
    hi = __shfl(hi, lane);
    return ((unsigned long long)hi << 32) | lo;
}
__device__ __forceinline__ unsigned quant12(float v) {
    int b = (int)(__float_as_uint(v) >> 13) - QB;
    b = b < 1 ? 1 : (b > NBINS - 1 ? NBINS - 1 : b);
    return (unsigned)b;
}

// One block per channel: stream NMS -> LDS candidates -> in-block exact top-30.
// LDS: 32K buf + 16K hist + 1K gsum + 2K ref + ctrl ~= 52.2 KB -> 3 blocks/CU.
__global__ __launch_bounds__(256)
void pose_fused_kernel(const float* __restrict__ heat, float* __restrict__ out, int out_size) {
    __shared__ unsigned s_buf[CAP];             // (q12 << 16) | pixel_idx
    __shared__ int s_hist[NBINS];
    __shared__ int s_gsum[256];                 // each = sum of 16 bins
    __shared__ unsigned long long s_ref[256];   // exact keys
    __shared__ int s_cnt, s_nref, s_tau;

    const int tid  = threadIdx.x;
    const int chan = blockIdx.x;
    const int wave = tid >> 6;
    const int lane = tid & 63;
    const float NEGINF = -__builtin_inff();
    const float* __restrict__ cp = heat + (size_t)chan * (HDIM * WDIM);

    for (int i = tid; i < NBINS; i += 256) s_hist[i] = 0;
    if (tid == 0) { s_cnt = 0; s_nref = 0; }
    __syncthreads();

    // ---- Phase 1: NMS. Wave w streams rows [64w, 64w+64), rolling registers ----
    const int r0 = wave << 6;
    const float* colp = cp + (lane << 2);
    const float4 NEG4 = make_float4(NEGINF, NEGINF, NEGINF, NEGINF);

    float4 rm = (r0 > 0) ? *(const float4*)(colp + ((r0 - 1) << 8)) : NEG4;
    float4 rc = *(const float4*)(colp + (r0 << 8));

    for (int rr = 0; rr < 64; ++rr) {
        const int r = r0 + rr;
        float4 rp = (r + 1 < HDIM) ? *(const float4*)(colp + ((r + 1) << 8)) : NEG4;

        float vm0 = fmaxf(rm.x, fmaxf(rc.x, rp.x));
        float vm1 = fmaxf(rm.y, fmaxf(rc.y, rp.y));
        float vm2 = fmaxf(rm.z, fmaxf(rc.z, rp.z));
        float vm3 = fmaxf(rm.w, fmaxf(rc.w, rp.w));
        float left  = __shfl_up(vm3, 1);   if (lane == 0)  left  = NEGINF;
        float right = __shfl_down(vm0, 1); if (lane == 63) right = NEGINF;
        float h0 = fmaxf(left, fmaxf(vm0, vm1));
        float h1 = fmaxf(vm0, fmaxf(vm1, vm2));
        float h2 = fmaxf(vm1, fmaxf(vm2, vm3));
        float h3 = fmaxf(vm2, fmaxf(vm3, right));

        const int base = (r << 8) | (lane << 2);
        if (rc.x > 0.1f && rc.x == h0) {
            int pos = atomicAdd(&s_cnt, 1);
            if (pos < CAP) s_buf[pos] = (quant12(rc.x) << 16) | (unsigned)(base + 0);
        }
        if (rc.y > 0.1f && rc.y == h1) {
            int pos = atomicAdd(&s_cnt, 1);
            if (pos < CAP) s_buf[pos] = (quant12(rc.y) << 16) | (unsigned)(base + 1);
        }
        if (rc.z > 0.1f && rc.z == h2) {
            int pos = atomicAdd(&s_cnt, 1);
            if (pos < CAP) s_buf[pos] = (quant12(rc.z) << 16) | (unsigned)(base + 2);
        }
        if (rc.w > 0.1f && rc.w == h3) {
            int pos = atomicAdd(&s_cnt, 1);
            if (pos < CAP) s_buf[pos] = (quant12(rc.w) << 16) | (unsigned)(base + 3);
        }
        rm = rc; rc = rp;
    }
    __syncthreads();

    // ---- Phase 2: histogram on quantized score (candidates already in LDS) ----
    const int n = s_cnt < CAP ? s_cnt : CAP;
    for (int i = tid; i < n; i += 256) {
        atomicAdd(&s_hist[s_buf[i] >> 16], 1);
    }
    __syncthreads();

    {   // two-level suffix scan: 256 groups of 16 bins
        int s = 0;
        #pragma unroll
        for (int j = 0; j < 16; ++j) s += s_hist[tid * 16 + j];
        s_gsum[tid] = s;
    }
    __syncthreads();
    if (tid == 0) {
        int cum = 0, tau = 0;
        for (int g = 255; g >= 0; --g) {
            int gs = s_gsum[g];
            if (cum + gs >= MAXP) {
                for (int b = g * 16 + 15; b >= g * 16; --b) {
                    cum += s_hist[b];
                    if (cum >= MAXP) { tau = b; break; }
                }
                break;
            }
            cum += gs;
        }
        s_tau = tau;   // 0 if total < MAXP -> collect all
    }
    __syncthreads();

    // ---- Phase 3: collect survivors (q >= tau), re-read exact scores (~62, L2-hot) ----
    const unsigned tau = (unsigned)s_tau;
    for (int i = tid; i < n; i += 256) {
        unsigned p = s_buf[i];
        if ((p >> 16) >= tau) {
            int pos = atomicAdd(&s_nref, 1);
            if (pos < 256) {
                unsigned idx = p & 0xFFFFu;
                float sc = cp[idx];
                // key: higher score wins; tie -> smaller idx (matches lax.top_k)
                s_ref[pos] = ((unsigned long long)__float_as_uint(sc) << 32) | (unsigned)(~idx);
            }
        }
    }
    __syncthreads();
    const int nref = s_nref < 256 ? s_nref : 256;

    // ---- Phase 4: exact top-30 extraction, wave 0 only ----
    if (tid < 64) {
        unsigned long long k0 = (tid       < nref) ? s_ref[tid]       : 0ull;
        unsigned long long k1 = (tid + 64  < nref) ? s_ref[tid + 64]  : 0ull;
        unsigned long long k2 = (tid + 128 < nref) ? s_ref[tid + 128] : 0ull;
        unsigned long long k3 = (tid + 192 < nref) ? s_ref[tid + 192] : 0ull;
        for (int r = 0; r < MAXP; ++r) {
            unsigned long long best = k0; int bs = 0;
            if (k1 > best) { best = k1; bs = 1; }
            if (k2 > best) { best = k2; bs = 2; }
            if (k3 > best) { best = k3; bs = 3; }
            unsigned long long key = best;
            int slot = (bs << 6) | tid;
            #pragma unroll
            for (int off = 32; off > 0; off >>= 1) {
                unsigned long long ok = shfl_down_u64(key, off);
                int os = __shfl_down(slot, off);
                if (ok > key) { key = ok; slot = os; }
            }
            key  = shfl_u64(key, 0);
            slot = __shfl(slot, 0);
            if ((slot & 63) == tid) {           // winner's owner removes it
                int which = slot >> 6;
                if      (which == 0) k0 = 0ull;
                else if (which == 1) k1 = 0ull;
                else if (which == 2) k2 = 0ull;
                else                 k3 = 0ull;
            }
            if (tid == 0) {
                float sc, vld; unsigned idx;
                if (key != 0ull) {
                    sc  = __uint_as_float((unsigned)(key >> 32));
                    idx = (~(unsigned)key) & 0xFFFFu;
                    vld = 1.0f;
                } else { sc = NEGINF; idx = 0u; vld = 0.0f; }
                int x = (int)(idx & 255), y = (int)(idx >> 8);
                long long cb = ((long long)chan * MAXP + r) * 2;
                if (cb + 1 < out_size) {
                    out[cb]     = (float)(x * 4);   // (x, y) * STRIDE
                    out[cb + 1] = (float)(y * 4);
                }
                long long so = (long long)NCH * MAXP * 2 + (long long)chan * MAXP + r;
                if (so < out_size) out[so] = sc;
                long long vo = (long long)NCH * MAXP * 3 + (long long)chan * MAXP + r;
                if (vo < out_size) out[vo] = vld;
            }
        }
    }
}

extern "C" void kernel_launch(void* const* d_in, const int* in_sizes, int n_in,
                              void* d_out, int out_size, void* d_ws, size_t ws_size,
                              hipStream_t stream) {
    const float* heat = (const float*)d_in[0];
    float* out = (float*)d_out;
    hipLaunchKernelGGL(pose_fused_kernel, dim3(NCH), dim3(256), 0, stream, heat, out, out_size);
}

// Round 6
// 238.092 us; speedup vs baseline: 1.0915x; 1.0915x over previous
//
#include <hip/hip_runtime.h>
#include <stdint.h>

#define NUM_KP 17
#define BATCH  32
#define HDIM   256
#define WDIM   256
#define NCH    (BATCH * NUM_KP)     // 544 channels
#define MAXP   30
#define CAP    8192                 // per-channel candidate cap (E~7340, +10 sigma)

// 12-bit score quantization: q = (float_bits >> 13) - QB, clamped [1, 4095].
// Scores in (0.1, 1] map to bins [613, 4095]; ~32 candidates land in the top
// bin for uniform-noise NMS maxima -> survivors ~= 62 +- 8 << 256.
#define NBINS  4096
#define QB     125953               // (0x3F800000 >> 13) - 4095

#define THREADS 512                 // 8 waves; 2 blocks/CU -> 17 waves/CU resident

__device__ __forceinline__ unsigned long long shfl_down_u64(unsigned long long v, int off) {
    unsigned lo = (unsigned)v, hi = (unsigned)(v >> 32);
    lo = __shfl_down(lo, off);
    hi = __shfl_down(hi, off);
    return ((unsigned long long)hi << 32) | lo;
}
__device__ __forceinline__ unsigned long long shfl_u64(unsigned long long v, int lane) {
    unsigned lo = (unsigned)v, hi = (unsigned)(v >> 32);
    lo = __shfl(lo, lane);
    hi = __shfl(hi, lane);
    return ((unsigned long long)hi << 32) | lo;
}
__device__ __forceinline__ unsigned quant12(float v) {
    int b = (int)(__float_as_uint(v) >> 13) - QB;
    b = b < 1 ? 1 : (b > NBINS - 1 ? NBINS - 1 : b);
    return (unsigned)b;
}

// One block per channel: streaming NMS (4-deep prefetch, wave-aggregated LDS
// append) -> in-LDS histogram top-30. LDS ~= 52.2 KB -> 2 blocks/CU at 512 thr.
__global__ __launch_bounds__(THREADS, 4)
void pose_fused_kernel(const float* __restrict__ heat, float* __restrict__ out, int out_size) {
    __shared__ unsigned s_buf[CAP];             // (q12 << 16) | pixel_idx
    __shared__ int s_hist[NBINS];
    __shared__ int s_gsum[256];                 // each = sum of 16 bins
    __shared__ unsigned long long s_ref[256];   // exact keys
    __shared__ int s_cnt, s_nref, s_tau;

    const int tid  = threadIdx.x;
    const int chan = blockIdx.x;
    const int wave = tid >> 6;
    const int lane = tid & 63;
    const float NEGINF = -__builtin_inff();
    const float* __restrict__ cp = heat + (size_t)chan * (HDIM * WDIM);

    for (int i = tid; i < NBINS; i += THREADS) s_hist[i] = 0;
    if (tid == 0) { s_cnt = 0; s_nref = 0; }
    __syncthreads();

    // ---- Phase 1: NMS. Wave w streams rows [32w, 32w+32) in groups of 4,
    //      next group's 4 loads issued before current group's compute. ----
    const int r0 = wave << 5;
    const float* colp = cp + (lane << 2);
    const float4 NEG4 = make_float4(NEGINF, NEGINF, NEGINF, NEGINF);
    const unsigned long long ltmask = (1ull << lane) - 1ull;

    auto LD = [&](int r) -> float4 {
        return (r >= 0 && r < HDIM) ? *(const float4*)(colp + (r << 8)) : NEG4;
    };

    auto process = [&](const float4& up, const float4& md, const float4& dn, int r) {
        float vm0 = fmaxf(up.x, fmaxf(md.x, dn.x));
        float vm1 = fmaxf(up.y, fmaxf(md.y, dn.y));
        float vm2 = fmaxf(up.z, fmaxf(md.z, dn.z));
        float vm3 = fmaxf(up.w, fmaxf(md.w, dn.w));
        float left  = __shfl_up(vm3, 1);   if (lane == 0)  left  = NEGINF;
        float right = __shfl_down(vm0, 1); if (lane == 63) right = NEGINF;
        float h0 = fmaxf(left, fmaxf(vm0, vm1));
        float h1 = fmaxf(vm0, fmaxf(vm1, vm2));
        float h2 = fmaxf(vm1, fmaxf(vm2, vm3));
        float h3 = fmaxf(vm2, fmaxf(vm3, right));

        bool p0 = md.x > 0.1f && md.x == h0;
        bool p1 = md.y > 0.1f && md.y == h1;
        bool p2 = md.z > 0.1f && md.z == h2;
        bool p3 = md.w > 0.1f && md.w == h3;
        unsigned long long b0 = __ballot(p0), b1 = __ballot(p1);
        unsigned long long b2 = __ballot(p2), b3 = __ballot(p3);
        int c0 = __popcll(b0), c1 = __popcll(b1), c2 = __popcll(b2), c3 = __popcll(b3);
        int tot = c0 + c1 + c2 + c3;
        int wb = 0;
        if (lane == 0 && tot > 0) wb = atomicAdd(&s_cnt, tot);  // ONE atomic per wave-row
        wb = __shfl(wb, 0);

        const int base = (r << 8) | (lane << 2);
        if (p0) { int pos = wb + __popcll(b0 & ltmask);
                  if (pos < CAP) s_buf[pos] = (quant12(md.x) << 16) | (unsigned)(base + 0); }
        if (p1) { int pos = wb + c0 + __popcll(b1 & ltmask);
                  if (pos < CAP) s_buf[pos] = (quant12(md.y) << 16) | (unsigned)(base + 1); }
        if (p2) { int pos = wb + c0 + c1 + __popcll(b2 & ltmask);
                  if (pos < CAP) s_buf[pos] = (quant12(md.z) << 16) | (unsigned)(base + 2); }
        if (p3) { int pos = wb + c0 + c1 + c2 + __popcll(b3 & ltmask);
                  if (pos < CAP) s_buf[pos] = (quant12(md.w) << 16) | (unsigned)(base + 3); }
    };

    float4 rm   = LD(r0 - 1);
    float4 cur0 = LD(r0 + 0), cur1 = LD(r0 + 1), cur2 = LD(r0 + 2), cur3 = LD(r0 + 3);

    #pragma unroll
    for (int g = 0; g < 8; ++g) {
        const int rb = r0 + (g << 2);
        float4 n0, n1, n2, n3;
        if (g < 7) {            // compile-time resolved: full prefetch of next group
            n0 = LD(rb + 4); n1 = LD(rb + 5); n2 = LD(rb + 6); n3 = LD(rb + 7);
        } else {                // tail: only the down-halo row is needed
            n0 = LD(rb + 4); n1 = NEG4; n2 = NEG4; n3 = NEG4;
        }
        process(rm,   cur0, cur1, rb + 0);
        process(cur0, cur1, cur2, rb + 1);
        process(cur1, cur2, cur3, rb + 2);
        process(cur2, cur3, n0,   rb + 3);
        rm = cur3; cur0 = n0; cur1 = n1; cur2 = n2; cur3 = n3;
    }
    __syncthreads();

    // ---- Phase 2: histogram on quantized score ----
    const int n = s_cnt < CAP ? s_cnt : CAP;
    for (int i = tid; i < n; i += THREADS) {
        atomicAdd(&s_hist[s_buf[i] >> 16], 1);
    }
    __syncthreads();

    if (tid < 256) {            // two-level suffix scan: 256 groups of 16 bins
        int s = 0;
        #pragma unroll
        for (int j = 0; j < 16; ++j) s += s_hist[tid * 16 + j];
        s_gsum[tid] = s;
    }
    __syncthreads();
    if (tid == 0) {
        int cum = 0, tau = 0;
        for (int g = 255; g >= 0; --g) {
            int gs = s_gsum[g];
            if (cum + gs >= MAXP) {
                for (int b = g * 16 + 15; b >= g * 16; --b) {
                    cum += s_hist[b];
                    if (cum >= MAXP) { tau = b; break; }
                }
                break;
            }
            cum += gs;
        }
        s_tau = tau;   // 0 if total < MAXP -> collect all
    }
    __syncthreads();

    // ---- Phase 3: collect survivors (q >= tau), re-read exact scores (~62, L2-hot) ----
    const unsigned tau = (unsigned)s_tau;
    for (int i = tid; i < n; i += THREADS) {
        unsigned p = s_buf[i];
        if ((p >> 16) >= tau) {
            int pos = atomicAdd(&s_nref, 1);
            if (pos < 256) {
                unsigned idx = p & 0xFFFFu;
                float sc = cp[idx];
                // key: higher score wins; tie -> smaller idx (matches lax.top_k)
                s_ref[pos] = ((unsigned long long)__float_as_uint(sc) << 32) | (unsigned)(~idx);
            }
        }
    }
    __syncthreads();
    const int nref = s_nref < 256 ? s_nref : 256;

    // ---- Phase 4: exact top-30 extraction, wave 0 only ----
    if (tid < 64) {
        unsigned long long k0 = (tid       < nref) ? s_ref[tid]       : 0ull;
        unsigned long long k1 = (tid + 64  < nref) ? s_ref[tid + 64]  : 0ull;
        unsigned long long k2 = (tid + 128 < nref) ? s_ref[tid + 128] : 0ull;
        unsigned long long k3 = (tid + 192 < nref) ? s_ref[tid + 192] : 0ull;
        for (int r = 0; r < MAXP; ++r) {
            unsigned long long best = k0; int bs = 0;
            if (k1 > best) { best = k1; bs = 1; }
            if (k2 > best) { best = k2; bs = 2; }
            if (k3 > best) { best = k3; bs = 3; }
            unsigned long long key = best;
            int slot = (bs << 6) | tid;
            #pragma unroll
            for (int off = 32; off > 0; off >>= 1) {
                unsigned long long ok = shfl_down_u64(key, off);
                int os = __shfl_down(slot, off);
                if (ok > key) { key = ok; slot = os; }
            }
            key  = shfl_u64(key, 0);
            slot = __shfl(slot, 0);
            if ((slot & 63) == tid) {           // winner's owner removes it
                int which = slot >> 6;
                if      (which == 0) k0 = 0ull;
                else if (which == 1) k1 = 0ull;
                else if (which == 2) k2 = 0ull;
                else                 k3 = 0ull;
            }
            if (tid == 0) {
                float sc, vld; unsigned idx;
                if (key != 0ull) {
                    sc  = __uint_as_float((unsigned)(key >> 32));
                    idx = (~(unsigned)key) & 0xFFFFu;
                    vld = 1.0f;
                } else { sc = NEGINF; idx = 0u; vld = 0.0f; }
                int x = (int)(idx & 255), y = (int)(idx >> 8);
                long long cb = ((long long)chan * MAXP + r) * 2;
                if (cb + 1 < out_size) {
                    out[cb]     = (float)(x * 4);   // (x, y) * STRIDE
                    out[cb + 1] = (float)(y * 4);
                }
                long long so = (long long)NCH * MAXP * 2 + (long long)chan * MAXP + r;
                if (so < out_size) out[so] = sc;
                long long vo = (long long)NCH * MAXP * 3 + (long long)chan * MAXP + r;
                if (vo < out_size) out[vo] = vld;
            }
        }
    }
}

extern "C" void kernel_launch(void* const* d_in, const int* in_sizes, int n_in,
                              void* d_out, int out_size, void* d_ws, size_t ws_size,
                              hipStream_t stream) {
    const float* heat = (const float*)d_in[0];
    float* out = (float*)d_out;
    hipLaunchKernelGGL(pose_fused_kernel, dim3(NCH), dim3(THREADS), 0, stream, heat, out, out_size);
}